// Round 1
// baseline (253.445 us; speedup 1.0000x reference)
//
#include <hip/hip_runtime.h>
#include <math.h>

#define W_IN     16384
#define FLT      32
#define W_OUT    (W_IN - FLT + 1)      // 16353
#define TILE_OUT 2048
#define TILE_IN  (TILE_OUT + 64)       // 2112: covers MFMA B-reads to s+303
#define NT       256
#define N_TILES  8
#define LUT_N    2048
#define LUT_MAXM 16.0f                 // inputs are N(0,1); max mag ~6.2 << 16
#define LUT_SCL  (LUT_N / LUT_MAXM)    // 128.0f
#define OUT_SCALE 0.17782794100389228f // sqrt(10^(-15/10)); folded into taps

#define ARR_B (TILE_IN * 2)            // 4224 bytes per bf16 plane in LDS

typedef short  short8 __attribute__((ext_vector_type(8)));   // 8 bf16 = 4 VGPR
typedef float  f32x4  __attribute__((ext_vector_type(4)));   // MFMA acc

// 16B-chunk XOR swizzle: spreads the quarter-wave (even-chunk) read phase
// across all 8 bank-groups. Bijective within each 128B block.
__device__ __forceinline__ int swz16(int b) {
    return b ^ (((b >> 7) & 7) << 4);
}

// Truncate-split f32 -> bf16 hi + bf16 lo. x == hi + lo + O(2^-17 * x).
__device__ __forceinline__ void bsplit(float x, unsigned short& h, unsigned short& l) {
    const unsigned u = __float_as_uint(x);
    h = (unsigned short)(u >> 16);
    const float rem = x - __uint_as_float(u & 0xffff0000u);  // exact
    l = (unsigned short)(__float_as_uint(rem) >> 16);
}

// ---- pre-kernel: build g(mag) = (sum_j c2_j * tanh(c1_j*mag)) / mag LUT ----
__global__ void build_lut_kernel(const float* __restrict__ w1,
                                 const float* __restrict__ w2,
                                 float* __restrict__ lut) {
    const int k = blockIdx.x * blockDim.x + threadIdx.x;
    if (k >= LUT_N) return;
    float c1[8], c2[8];
#pragma unroll
    for (int j = 0; j < 8; ++j) { c1[j] = w1[j]; c2[j] = w2[j]; }
    if (k == 0) {
        float g0 = 0.f;
#pragma unroll
        for (int j = 0; j < 8; ++j) g0 += c2[j] * c1[j];   // lim h(m)/m
        lut[0] = g0;
    } else {
        const float m = (float)k * (LUT_MAXM / LUT_N);
        float h = 0.f;
#pragma unroll
        for (int j = 0; j < 8; ++j) h += c2[j] * tanhf(c1[j] * m);
        lut[k] = h / m;
    }
}

#define MFMA(a, b, c) __builtin_amdgcn_mfma_f32_16x16x32_bf16((a), (b), (c), 0, 0, 0)

__global__ __launch_bounds__(NT, 4)
void fused_env_mlp_fir_kernel(const float* __restrict__ xr,
                              const float* __restrict__ xi,
                              const float* __restrict__ lut_g,
                              const float* __restrict__ wlr,  // [32]
                              const float* __restrict__ wli,  // [32]
                              float* __restrict__ out)        // [1024, 16353, 2]
{
    // 4 bf16 planes: xr_hi | xr_lo | xi_hi | xi_lo (chunk-swizzled)
    __shared__ __align__(16) unsigned short sx[4 * TILE_IN];
    __shared__ float slut[LUT_N];
    __shared__ float staps[64];        // fr*SCALE [0..31], fi*SCALE [32..63]

    const int bid    = blockIdx.x;
    const int row    = bid >> 3;         // 0..1023
    const int tile   = bid & 7;          // 0..7
    const int tstart = tile * TILE_OUT;
    const int tid    = threadIdx.x;
    const int lane   = tid & 63;

    // ---- LUT + scaled taps -> LDS ----
    for (int i = tid; i < LUT_N / 4; i += NT)
        *(float4*)(slut + 4 * i) = *(const float4*)(lut_g + 4 * i);
    if (tid < 32)       staps[tid] = wlr[tid] * OUT_SCALE;
    else if (tid < 64)  staps[tid] = wli[tid - 32] * OUT_SCALE;
    __syncthreads();

    const float* __restrict__ xr_row = xr + (size_t)row * W_IN;
    const float* __restrict__ xi_row = xi + (size_t)row * W_IN;

    // ---- Stage 1: global -> envelope+MLP (LUT) -> bf16 hi/lo planes in LDS ----
    for (int c = tid; c < TILE_IN / 4; c += NT) {      // 528 float4-chunks
        const int g = tstart + 4 * c;
        float4 vr, vi;
        if (g + 3 < W_IN) {
            vr = *(const float4*)(xr_row + g);
            vi = *(const float4*)(xi_row + g);
        } else {
            vr = make_float4(0.f, 0.f, 0.f, 0.f);
            vi = make_float4(0.f, 0.f, 0.f, 0.f);
        }
        const float ar[4] = {vr.x, vr.y, vr.z, vr.w};
        const float ai[4] = {vi.x, vi.y, vi.z, vi.w};
        unsigned short rha[4], rla[4], iha[4], ila[4];
#pragma unroll
        for (int e = 0; e < 4; ++e) {
            const float a = ar[e], b = ai[e];
            const float s = fmaxf(fmaf(a, a, b * b), 1e-30f);
            const float rs = rsqrtf(s);
            const float mag  = s * rs;               // sqrt(s), fast
            const float idxf = mag * LUT_SCL;
            int i = (int)idxf;
            i = min(i, LUT_N - 2);
            const float fr = idxf - (float)i;
            const float g0 = slut[i], g1 = slut[i + 1];
            const float gg = fmaf(fr, g1 - g0, g0);  // h(mag)/mag
            bsplit(a * gg, rha[e], rla[e]);          // h*cos(phase)
            bsplit(b * gg, iha[e], ila[e]);          // h*sin(phase)
        }
        const int pb = swz16(8 * c);                 // 8B granular, chunk-swizzled
        char* sb = (char*)sx;
        *(ushort4*)(sb + 0 * ARR_B + pb) = make_ushort4(rha[0], rha[1], rha[2], rha[3]);
        *(ushort4*)(sb + 1 * ARR_B + pb) = make_ushort4(rla[0], rla[1], rla[2], rla[3]);
        *(ushort4*)(sb + 2 * ARR_B + pb) = make_ushort4(iha[0], iha[1], iha[2], iha[3]);
        *(ushort4*)(sb + 3 * ARR_B + pb) = make_ushort4(ila[0], ila[1], ila[2], ila[3]);
    }

    // ---- Banded-Toeplitz filter A-fragments (per-lane, scale folded in) ----
    // A[m][k], m = lane&15, k = 8*(lane>>4)+e. Chunk c: tap t = k - m + 32c.
    short8 frh[2], frl[2], fih[2], fil[2];
    {
        const int fm  = lane & 15;
        const int fk0 = (lane >> 4) << 3;
#pragma unroll
        for (int c = 0; c < 2; ++c) {
#pragma unroll
            for (int e = 0; e < 8; ++e) {
                const int t = fk0 + e - fm + 32 * c;
                const bool v = ((unsigned)t < 32u);
                const int ti = v ? t : 0;
                const float fr_ = v ? staps[ti]      : 0.f;
                const float fi_ = v ? staps[32 + ti] : 0.f;
                unsigned short h, l;
                bsplit(fr_, h, l); frh[c][e] = (short)h; frl[c][e] = (short)l;
                bsplit(fi_, h, l); fih[c][e] = (short)h; fil[c][e] = (short)l;
            }
        }
    }
    __syncthreads();

    // ---- Stage 2: FIR via MFMA. D[m][q] = out[s+16q+m], 256 outputs/group ----
    const int wid = tid >> 6;
    const int rr  = lane & 15;           // fragment n (output col)
    const int jj  = lane >> 4;           // k-subgroup
    float* __restrict__ out_row = out + (size_t)row * (W_OUT * 2);
    const int remain = W_OUT - tstart;
    const char* sb = (const char*)sx;

    const short8 sgn = {(short)0x8000, (short)0x8000, (short)0x8000, (short)0x8000,
                        (short)0x8000, (short)0x8000, (short)0x8000, (short)0x8000};

#pragma unroll
    for (int gi = 0; gi < 2; ++gi) {
        const int grp = wid + 4 * gi;    // 8 groups of 256 outputs
        const int s   = grp << 8;
        // B-fragment: X[k][n] = x'[s + 16n + k (+32)], 8 contiguous bf16/lane
        const int bl = 2 * s + 32 * rr + 16 * jj;
        const int a0 = swz16(bl);
        const int a1 = swz16(bl + 64);
        const short8 xrh0 = *(const short8*)(sb + 0 * ARR_B + a0);
        const short8 xrh1 = *(const short8*)(sb + 0 * ARR_B + a1);
        const short8 xrl0 = *(const short8*)(sb + 1 * ARR_B + a0);
        const short8 xrl1 = *(const short8*)(sb + 1 * ARR_B + a1);
        const short8 xih0 = *(const short8*)(sb + 2 * ARR_B + a0);
        const short8 xih1 = *(const short8*)(sb + 2 * ARR_B + a1);
        const short8 xil0 = *(const short8*)(sb + 3 * ARR_B + a0);
        const short8 xil1 = *(const short8*)(sb + 3 * ARR_B + a1);
        const short8 nih0 = xih0 ^ sgn;  // -xi (bf16 sign flip, exact)
        const short8 nih1 = xih1 ^ sgn;
        const short8 nil0 = xil0 ^ sgn;
        const short8 nil1 = xil1 ^ sgn;

        f32x4 accr = {0.f, 0.f, 0.f, 0.f};
        f32x4 acci = {0.f, 0.f, 0.f, 0.f};
        // yr = fr (x) xr + fi (x) (-xi);  yi = fr (x) xi + fi (x) xr
        // 3-product hi/lo split each; interleave the two acc chains for ILP.
        accr = MFMA(frh[0], xrh0, accr);  acci = MFMA(frh[0], xih0, acci);
        accr = MFMA(frh[1], xrh1, accr);  acci = MFMA(frh[1], xih1, acci);
        accr = MFMA(fih[0], nih0, accr);  acci = MFMA(fih[0], xrh0, acci);
        accr = MFMA(fih[1], nih1, accr);  acci = MFMA(fih[1], xrh1, acci);
        accr = MFMA(frh[0], xrl0, accr);  acci = MFMA(frh[0], xil0, acci);
        accr = MFMA(frh[1], xrl1, accr);  acci = MFMA(frh[1], xil1, acci);
        accr = MFMA(frl[0], xrh0, accr);  acci = MFMA(frl[0], xih0, acci);
        accr = MFMA(frl[1], xrh1, accr);  acci = MFMA(frl[1], xih1, acci);
        accr = MFMA(fih[0], nil0, accr);  acci = MFMA(fih[0], xrl0, acci);
        accr = MFMA(fih[1], nil1, accr);  acci = MFMA(fih[1], xrl1, acci);
        accr = MFMA(fil[0], nih0, accr);  acci = MFMA(fil[0], xrh0, acci);
        accr = MFMA(fil[1], nih1, accr);  acci = MFMA(fil[1], xrh1, acci);

        // D lane layout: col=lane&15, row=4*(lane>>4)+reg -> 4 consecutive
        // outputs per lane. Store interleaved (yr,yi) directly: 2x dwordx4,
        // wave covers a contiguous 2KB span -> fully coalesced.
        const int p0 = s + 16 * rr + 4 * jj;
        float* dst = out_row + (size_t)(tstart + p0) * 2;
        if (p0 + 3 < remain) {
            *(float4*)(dst)     = make_float4(accr[0], acci[0], accr[1], acci[1]);
            *(float4*)(dst + 4) = make_float4(accr[2], acci[2], accr[3], acci[3]);
        } else {
#pragma unroll
            for (int q = 0; q < 4; ++q)
                if (p0 + q < remain)
                    *(float2*)(dst + 2 * q) = make_float2(accr[q], acci[q]);
        }
    }
}

extern "C" void kernel_launch(void* const* d_in, const int* in_sizes, int n_in,
                              void* d_out, int out_size, void* d_ws, size_t ws_size,
                              hipStream_t stream) {
    const float* xr  = (const float*)d_in[0];
    const float* xi  = (const float*)d_in[1];
    const float* w1  = (const float*)d_in[2];
    const float* w2  = (const float*)d_in[3];
    const float* wlr = (const float*)d_in[4];
    const float* wli = (const float*)d_in[5];
    float* out = (float*)d_out;
    float* lut = (float*)d_ws;                       // 2048 floats, rebuilt every call

    build_lut_kernel<<<dim3(LUT_N / NT), dim3(NT), 0, stream>>>(w1, w2, lut);

    const int rows = 16 * 64;                        // B*H = 1024
    fused_env_mlp_fir_kernel<<<dim3(rows * N_TILES), dim3(NT), 0, stream>>>(
        xr, xi, lut, wlr, wli, out);
}

// Round 2
// 250.664 us; speedup vs baseline: 1.0111x; 1.0111x over previous
//
#include <hip/hip_runtime.h>
#include <math.h>

#define W_IN     16384
#define FLT      32
#define W_OUT    (W_IN - FLT + 1)      // 16353
#define TILE_OUT 2048
#define TILE_IN  (TILE_OUT + 64)       // 2112: covers MFMA B-reads to s+2095
#define NT       256
#define N_TILES  8
#define UPB      4                     // units (row,tile) per block
#define LUT_N    2048
#define LUT_MAXM 16.0f                 // inputs are N(0,1); max mag ~6.2 << 16
#define LUT_SCL  (LUT_N / LUT_MAXM)    // 128.0f
#define OUT_SCALE 0.17782794100389228f // sqrt(10^(-15/10)); folded into taps

#define ARR_B (TILE_IN * 2)            // 4224 bytes per bf16 plane in LDS

typedef short  short8 __attribute__((ext_vector_type(8)));   // 8 bf16 = 4 VGPR
typedef float  f32x4  __attribute__((ext_vector_type(4)));   // MFMA acc

// 16B-chunk XOR swizzle: spreads the quarter-wave (even-chunk) read phase
// across all 8 bank-groups. Bijective within each 128B block.
__device__ __forceinline__ int swz16(int b) {
    return b ^ (((b >> 7) & 7) << 4);
}

// Truncate-split f32 -> bf16 hi + bf16 lo. x == hi + lo + O(2^-17 * x).
__device__ __forceinline__ void bsplit(float x, unsigned short& h, unsigned short& l) {
    const unsigned u = __float_as_uint(x);
    h = (unsigned short)(u >> 16);
    const float rem = x - __uint_as_float(u & 0xffff0000u);  // exact
    l = (unsigned short)(__float_as_uint(rem) >> 16);
}

// ---- pre-kernel: build g(mag) = (sum_j c2_j * tanh(c1_j*mag)) / mag LUT ----
__global__ void build_lut_kernel(const float* __restrict__ w1,
                                 const float* __restrict__ w2,
                                 float* __restrict__ lut) {
    const int k = blockIdx.x * blockDim.x + threadIdx.x;
    if (k >= LUT_N) return;
    float c1[8], c2[8];
#pragma unroll
    for (int j = 0; j < 8; ++j) { c1[j] = w1[j]; c2[j] = w2[j]; }
    if (k == 0) {
        float g0 = 0.f;
#pragma unroll
        for (int j = 0; j < 8; ++j) g0 += c2[j] * c1[j];   // lim h(m)/m
        lut[0] = g0;
    } else {
        const float m = (float)k * (LUT_MAXM / LUT_N);
        float h = 0.f;
#pragma unroll
        for (int j = 0; j < 8; ++j) h += c2[j] * tanhf(c1[j] * m);
        lut[k] = h / m;
    }
}

#define MFMA(a, b, c) __builtin_amdgcn_mfma_f32_16x16x32_bf16((a), (b), (c), 0, 0, 0)

// Issue next unit's global loads into prefetch regs (no wait here; the
// compiler inserts the vmcnt at the consuming stage-1 of the next iteration).
#define LOAD_UNIT(u) do {                                                   \
    const int _row = (u) >> 3, _tile = (u) & 7;                             \
    const int _ts  = _tile * TILE_OUT;                                      \
    const float* __restrict__ _xr = xr + (size_t)_row * W_IN;               \
    const float* __restrict__ _xi = xi + (size_t)_row * W_IN;               \
    _Pragma("unroll")                                                       \
    for (int _it = 0; _it < 3; ++_it) {                                     \
        const int _c = tid + NT * _it;                                      \
        float4 _zr = make_float4(0.f, 0.f, 0.f, 0.f);                       \
        float4 _zi = make_float4(0.f, 0.f, 0.f, 0.f);                       \
        if (_c < TILE_IN / 4) {                                             \
            const int _g = _ts + 4 * _c;                                    \
            if (_g + 3 < W_IN) {                                            \
                _zr = *(const float4*)(_xr + _g);                           \
                _zi = *(const float4*)(_xi + _g);                           \
            }                                                               \
        }                                                                   \
        pvr[_it] = _zr; pvi[_it] = _zi;                                     \
    }                                                                       \
} while (0)

__global__ __launch_bounds__(NT, 4)
void fused_env_mlp_fir_kernel(const float* __restrict__ xr,
                              const float* __restrict__ xi,
                              const float* __restrict__ lut_g,
                              const float* __restrict__ wlr,  // [32]
                              const float* __restrict__ wli,  // [32]
                              float* __restrict__ out)        // [1024, 16353, 2]
{
    // 4 bf16 planes: xr_hi | xr_lo | xi_hi | xi_lo (chunk-swizzled)
    __shared__ __align__(16) unsigned short sx[4 * TILE_IN];
    __shared__ float slut[LUT_N];
    __shared__ float staps[64];        // fr*SCALE [0..31], fi*SCALE [32..63]

    const int tid  = threadIdx.x;
    const int lane = tid & 63;
    const int unit0 = blockIdx.x * UPB;          // 2048 blocks * 4 = 8192 units

    // ---- prefetch unit 0 (earliest possible issue) ----
    float4 pvr[3], pvi[3];
    LOAD_UNIT(unit0);

    // ---- LUT + scaled taps -> LDS ----
    for (int i = tid; i < LUT_N / 4; i += NT)
        *(float4*)(slut + 4 * i) = *(const float4*)(lut_g + 4 * i);
    if (tid < 32)       staps[tid] = wlr[tid] * OUT_SCALE;
    else if (tid < 64)  staps[tid] = wli[tid - 32] * OUT_SCALE;
    __syncthreads();

    // ---- Banded-Toeplitz filter A-fragments (once per block, scale folded) ----
    // A[m][k], m = lane&15, k = 8*(lane>>4)+e. Chunk c: tap t = k - m + 32c.
    short8 frh[2], frl[2], fih[2], fil[2];
    {
        const int fm  = lane & 15;
        const int fk0 = (lane >> 4) << 3;
#pragma unroll
        for (int c = 0; c < 2; ++c) {
#pragma unroll
            for (int e = 0; e < 8; ++e) {
                const int t = fk0 + e - fm + 32 * c;
                const bool v = ((unsigned)t < 32u);
                const int ti = v ? t : 0;
                const float fr_ = v ? staps[ti]      : 0.f;
                const float fi_ = v ? staps[32 + ti] : 0.f;
                unsigned short h, l;
                bsplit(fr_, h, l); frh[c][e] = (short)h; frl[c][e] = (short)l;
                bsplit(fi_, h, l); fih[c][e] = (short)h; fil[c][e] = (short)l;
            }
        }
    }

    const int wid = tid >> 6;
    const int rr  = lane & 15;           // fragment n (output col)
    const int jj  = lane >> 4;           // k-subgroup
    const char* sbr = (const char*)sx;
    const short8 sgn = {(short)0x8000, (short)0x8000, (short)0x8000, (short)0x8000,
                        (short)0x8000, (short)0x8000, (short)0x8000, (short)0x8000};

    for (int t = 0; t < UPB; ++t) {
        const int unit   = unit0 + t;
        const int row    = unit >> 3;
        const int tstart = (unit & 7) * TILE_OUT;

        // ---- Stage 1: prefetched regs -> envelope+MLP (LUT) -> LDS planes ----
#pragma unroll
        for (int it = 0; it < 3; ++it) {
            const int c = tid + NT * it;
            if (c < TILE_IN / 4) {
                const float4 vr = pvr[it], vi = pvi[it];
                const float ar[4] = {vr.x, vr.y, vr.z, vr.w};
                const float ai[4] = {vi.x, vi.y, vi.z, vi.w};
                unsigned short rha[4], rla[4], iha[4], ila[4];
#pragma unroll
                for (int e = 0; e < 4; ++e) {
                    const float a = ar[e], b = ai[e];
                    const float s = fmaxf(fmaf(a, a, b * b), 1e-30f);
                    const float rs = rsqrtf(s);
                    const float mag  = s * rs;               // sqrt(s), fast
                    const float idxf = mag * LUT_SCL;
                    int i = (int)idxf;
                    i = min(i, LUT_N - 2);
                    const float fr = idxf - (float)i;
                    const float g0 = slut[i], g1 = slut[i + 1];
                    const float gg = fmaf(fr, g1 - g0, g0);  // h(mag)/mag
                    bsplit(a * gg, rha[e], rla[e]);          // h*cos(phase)
                    bsplit(b * gg, iha[e], ila[e]);          // h*sin(phase)
                }
                const int pb = swz16(8 * c);                 // 8B, chunk-swizzled
                char* sb = (char*)sx;
                *(ushort4*)(sb + 0 * ARR_B + pb) = make_ushort4(rha[0], rha[1], rha[2], rha[3]);
                *(ushort4*)(sb + 1 * ARR_B + pb) = make_ushort4(rla[0], rla[1], rla[2], rla[3]);
                *(ushort4*)(sb + 2 * ARR_B + pb) = make_ushort4(iha[0], iha[1], iha[2], iha[3]);
                *(ushort4*)(sb + 3 * ARR_B + pb) = make_ushort4(ila[0], ila[1], ila[2], ila[3]);
            }
        }

        // ---- issue next unit's loads; they stay in flight across BOTH
        // barriers below (raw s_barrier + lgkmcnt-only waits; a __syncthreads
        // here would emit vmcnt(0) and serialize us on HBM latency) ----
        if (t != UPB - 1) LOAD_UNIT(unit + 1);

        asm volatile("s_waitcnt lgkmcnt(0)" ::: "memory");  // LDS writes visible
        __builtin_amdgcn_s_barrier();

        // ---- Stage 2: FIR via MFMA. D[m][q] = out[s+16q+m] ----
        float* __restrict__ out_row = out + (size_t)row * (W_OUT * 2);
        const int remain = W_OUT - tstart;

#pragma unroll
        for (int gi = 0; gi < 2; ++gi) {
            const int grp = wid + 4 * gi;    // 8 groups of 256 outputs
            const int s   = grp << 8;
            // B-fragment: X[k][n] = x'[s + 16n + k (+32)], 8 contiguous bf16
            const int bl = 2 * s + 32 * rr + 16 * jj;
            const int a0 = swz16(bl);
            const int a1 = swz16(bl + 64);
            const short8 xrh0 = *(const short8*)(sbr + 0 * ARR_B + a0);
            const short8 xrh1 = *(const short8*)(sbr + 0 * ARR_B + a1);
            const short8 xrl0 = *(const short8*)(sbr + 1 * ARR_B + a0);
            const short8 xrl1 = *(const short8*)(sbr + 1 * ARR_B + a1);
            const short8 xih0 = *(const short8*)(sbr + 2 * ARR_B + a0);
            const short8 xih1 = *(const short8*)(sbr + 2 * ARR_B + a1);
            const short8 xil0 = *(const short8*)(sbr + 3 * ARR_B + a0);
            const short8 xil1 = *(const short8*)(sbr + 3 * ARR_B + a1);
            const short8 nih0 = xih0 ^ sgn;  // -xi (bf16 sign flip, exact)
            const short8 nih1 = xih1 ^ sgn;
            const short8 nil0 = xil0 ^ sgn;
            const short8 nil1 = xil1 ^ sgn;

            f32x4 accr = {0.f, 0.f, 0.f, 0.f};
            f32x4 acci = {0.f, 0.f, 0.f, 0.f};
            // yr = fr (x) xr + fi (x) (-xi);  yi = fr (x) xi + fi (x) xr
            // 3-product hi/lo split; interleave the two acc chains for ILP.
            accr = MFMA(frh[0], xrh0, accr);  acci = MFMA(frh[0], xih0, acci);
            accr = MFMA(frh[1], xrh1, accr);  acci = MFMA(frh[1], xih1, acci);
            accr = MFMA(fih[0], nih0, accr);  acci = MFMA(fih[0], xrh0, acci);
            accr = MFMA(fih[1], nih1, accr);  acci = MFMA(fih[1], xrh1, acci);
            accr = MFMA(frh[0], xrl0, accr);  acci = MFMA(frh[0], xil0, acci);
            accr = MFMA(frh[1], xrl1, accr);  acci = MFMA(frh[1], xil1, acci);
            accr = MFMA(frl[0], xrh0, accr);  acci = MFMA(frl[0], xih0, acci);
            accr = MFMA(frl[1], xrh1, accr);  acci = MFMA(frl[1], xih1, acci);
            accr = MFMA(fih[0], nil0, accr);  acci = MFMA(fih[0], xrl0, acci);
            accr = MFMA(fih[1], nil1, accr);  acci = MFMA(fih[1], xrl1, acci);
            accr = MFMA(fil[0], nih0, accr);  acci = MFMA(fil[0], xrh0, acci);
            accr = MFMA(fil[1], nih1, accr);  acci = MFMA(fil[1], xrh1, acci);

            // D lane layout: col=lane&15, row=4*(lane>>4)+reg -> 4 consecutive
            // outputs per lane -> 2x dwordx4 interleaved (yr,yi), coalesced.
            const int p0 = s + 16 * rr + 4 * jj;
            float* dst = out_row + (size_t)(tstart + p0) * 2;
            if (p0 + 3 < remain) {
                *(float4*)(dst)     = make_float4(accr[0], acci[0], accr[1], acci[1]);
                *(float4*)(dst + 4) = make_float4(accr[2], acci[2], accr[3], acci[3]);
            } else {
#pragma unroll
                for (int q = 0; q < 4; ++q)
                    if (p0 + q < remain)
                        *(float2*)(dst + 2 * q) = make_float2(accr[q], acci[q]);
            }
        }

        // LDS reuse hazard: next stage-1 writes must not pass this wave's
        // stage-2 reads. lgkmcnt-only again; prefetch loads remain in flight.
        asm volatile("s_waitcnt lgkmcnt(0)" ::: "memory");
        __builtin_amdgcn_s_barrier();
    }
}

extern "C" void kernel_launch(void* const* d_in, const int* in_sizes, int n_in,
                              void* d_out, int out_size, void* d_ws, size_t ws_size,
                              hipStream_t stream) {
    const float* xr  = (const float*)d_in[0];
    const float* xi  = (const float*)d_in[1];
    const float* w1  = (const float*)d_in[2];
    const float* w2  = (const float*)d_in[3];
    const float* wlr = (const float*)d_in[4];
    const float* wli = (const float*)d_in[5];
    float* out = (float*)d_out;
    float* lut = (float*)d_ws;                       // 2048 floats, rebuilt every call

    build_lut_kernel<<<dim3(LUT_N / NT), dim3(NT), 0, stream>>>(w1, w2, lut);

    const int rows = 16 * 64;                        // B*H = 1024
    const int blocks = rows * N_TILES / UPB;         // 2048
    fused_env_mlp_fir_kernel<<<dim3(blocks), dim3(NT), 0, stream>>>(
        xr, xi, lut, wlr, wli, out);
}